// Round 3
// baseline (106.660 us; speedup 1.0000x reference)
//
#include <hip/hip_runtime.h>

// Problem constants (match reference setup_inputs()).
constexpr int S = 2048;   // N_SAMPLES
constexpr int C = 4096;   // N_CHANNELS
constexpr int K = 4;      // N_COMPONENTS

constexpr int BLOCK = 256;
constexpr int VEC = 16;                // channels per thread; BLOCK*VEC == C

// 4-byte-aligned float4: legal wide load for the gathered (dword-aligned but
// not 16B-aligned) component window.
typedef float f4u __attribute__((ext_vector_type(4), aligned(4)));
// Native 16B-aligned float vector for nontemporal stores (HIP float4 is a
// struct and rejected by __builtin_nontemporal_store).
typedef float f4n __attribute__((ext_vector_type(4)));

__global__ __launch_bounds__(BLOCK) void smf_kernel(
    const float* __restrict__ comp,      // K x C
    const float* __restrict__ contrib,   // S x K
    const float* __restrict__ shift,     // S x K
    float* __restrict__ out)             // S x C
{
    const int s = blockIdx.x;                  // one sample per block
    const int c = (int)threadIdx.x * VEC;      // 16 channels per thread

    // Per-sample params: blockIdx-uniform addresses -> scalar-load friendly.
    float w0[K], w1[K];
    int   m[K];
    int mmin = 1 << 30, mmax = -(1 << 30);
#pragma unroll
    for (int k = 0; k < K; ++k) {
        const float sh = shift[s * K + k];
        const float ct = contrib[s * K + k];
        const float mf = floorf(sh);
        const float f  = sh - mf;
        m[k]  = (int)mf;
        w0[k] = ct * (1.0f - f);
        w1[k] = ct * f;
        mmin = min(mmin, m[k]);
        mmax = max(mmax, m[k]);
    }

    float acc[VEC];
#pragma unroll
    for (int j = 0; j < VEC; ++j) acc[j] = 0.f;

    // Fast path: all tap indices for channels [c, c+15] in [0, C).
    // Tap indices span [c + mmin, c + VEC - 1 + mmax + 1].
    const bool fast = (c + mmin >= 0) && (c + VEC + mmax < C);
    if (fast) {
#pragma unroll
        for (int k = 0; k < K; ++k) {
            const float* p = comp + k * C + c + m[k];
            float v[VEC + 1];
#pragma unroll
            for (int q = 0; q < VEC / 4; ++q) {
                const f4u t = *(const f4u*)(p + 4 * q);
                v[4 * q + 0] = t.x; v[4 * q + 1] = t.y;
                v[4 * q + 2] = t.z; v[4 * q + 3] = t.w;
            }
            v[VEC] = p[VEC];
#pragma unroll
            for (int j = 0; j < VEC; ++j)
                acc[j] += w0[k] * v[j] + w1[k] * v[j + 1];
        }
    } else {
        // Edge path (first/last thread of a row only): masked scalar taps,
        // exactly the reference semantics.
#pragma unroll
        for (int j = 0; j < VEC; ++j) {
            const int cc = c + j;
#pragma unroll
            for (int k = 0; k < K; ++k) {
                const int i0 = cc + m[k];
                const int i1 = i0 + 1;
                const float g0 = (i0 >= 0 && i0 < C) ? comp[k * C + i0] : 0.f;
                const float g1 = (i1 >= 0 && i1 < C) ? comp[k * C + i1] : 0.f;
                acc[j] += w0[k] * g0 + w1[k] * g1;
            }
        }
    }

    // c is a multiple of 16 -> 16B-aligned coalesced stores. Output is
    // write-once: non-temporal to keep it from displacing the comp table.
    float* op = out + s * C + c;
#pragma unroll
    for (int q = 0; q < VEC / 4; ++q) {
        f4n st = { acc[4 * q + 0], acc[4 * q + 1],
                   acc[4 * q + 2], acc[4 * q + 3] };
        __builtin_nontemporal_store(st, (f4n*)(op + 4 * q));
    }
}

extern "C" void kernel_launch(void* const* d_in, const int* in_sizes, int n_in,
                              void* d_out, int out_size, void* d_ws, size_t ws_size,
                              hipStream_t stream) {
    // d_in[0] = inputs (S x C) -- unused by the math (shape only), never read.
    const float* comp    = (const float*)d_in[1];  // K x C
    const float* contrib = (const float*)d_in[2];  // S x K
    const float* shift   = (const float*)d_in[3];  // S x K
    float* out = (float*)d_out;                    // S x C

    smf_kernel<<<S, BLOCK, 0, stream>>>(comp, contrib, shift, out);
}

// Round 4
// 106.401 us; speedup vs baseline: 1.0024x; 1.0024x over previous
//
#include <hip/hip_runtime.h>

// Problem constants (match reference setup_inputs()).
constexpr int S = 2048;   // N_SAMPLES
constexpr int C = 4096;   // N_CHANNELS
constexpr int K = 4;      // N_COMPONENTS

constexpr int BLOCK = 256;
constexpr int VEC = 16;                // channels per thread; BLOCK*VEC == C

// 4-byte-aligned float4: legal wide load for the gathered (dword-aligned but
// not 16B-aligned) component window.
typedef float f4u __attribute__((ext_vector_type(4), aligned(4)));
// Native 16B-aligned float vector for the coalesced stores.
typedef float f4n __attribute__((ext_vector_type(4)));

__global__ __launch_bounds__(BLOCK) void smf_kernel(
    const float* __restrict__ comp,      // K x C
    const float* __restrict__ contrib,   // S x K
    const float* __restrict__ shift,     // S x K
    float* __restrict__ out)             // S x C
{
    const int s = blockIdx.x;                  // one sample per block
    const int c = (int)threadIdx.x * VEC;      // 16 channels per thread

    // Per-sample params: blockIdx-uniform addresses -> scalar-load friendly.
    float w0[K], w1[K];
    int   m[K];
    int mmin = 1 << 30, mmax = -(1 << 30);
#pragma unroll
    for (int k = 0; k < K; ++k) {
        const float sh = shift[s * K + k];
        const float ct = contrib[s * K + k];
        const float mf = floorf(sh);
        const float f  = sh - mf;
        m[k]  = (int)mf;
        w0[k] = ct * (1.0f - f);
        w1[k] = ct * f;
        mmin = min(mmin, m[k]);
        mmax = max(mmax, m[k]);
    }

    float acc[VEC];
#pragma unroll
    for (int j = 0; j < VEC; ++j) acc[j] = 0.f;

    // Fast path: all tap indices for channels [c, c+15] in [0, C).
    // Tap indices span [c + mmin, c + VEC - 1 + mmax + 1].
    const bool fast = (c + mmin >= 0) && (c + VEC + mmax < C);
    if (fast) {
#pragma unroll
        for (int k = 0; k < K; ++k) {
            const float* p = comp + k * C + c + m[k];
            float v[VEC + 1];
#pragma unroll
            for (int q = 0; q < VEC / 4; ++q) {
                const f4u t = *(const f4u*)(p + 4 * q);
                v[4 * q + 0] = t.x; v[4 * q + 1] = t.y;
                v[4 * q + 2] = t.z; v[4 * q + 3] = t.w;
            }
            v[VEC] = p[VEC];
#pragma unroll
            for (int j = 0; j < VEC; ++j)
                acc[j] += w0[k] * v[j] + w1[k] * v[j + 1];
        }
    } else {
        // Edge path (first/last thread of a row only): masked scalar taps,
        // exactly the reference semantics.
#pragma unroll
        for (int j = 0; j < VEC; ++j) {
            const int cc = c + j;
#pragma unroll
            for (int k = 0; k < K; ++k) {
                const int i0 = cc + m[k];
                const int i1 = i0 + 1;
                const float g0 = (i0 >= 0 && i0 < C) ? comp[k * C + i0] : 0.f;
                const float g1 = (i1 >= 0 && i1 < C) ? comp[k * C + i1] : 0.f;
                acc[j] += w0[k] * g0 + w1[k] * g1;
            }
        }
    }

    // c is a multiple of 16 -> 16B-aligned coalesced stores. PLAIN stores:
    // the 32 MB write-once output is absorbed by L2/L3 (256 MiB LLC) at
    // cache BW and written back to HBM after kernel end. Non-temporal
    // stores (tried R3) forced it to HBM inside the kernel: +11 us. 
    float* op = out + s * C + c;
#pragma unroll
    for (int q = 0; q < VEC / 4; ++q) {
        f4n st = { acc[4 * q + 0], acc[4 * q + 1],
                   acc[4 * q + 2], acc[4 * q + 3] };
        *(f4n*)(op + 4 * q) = st;
    }
}

extern "C" void kernel_launch(void* const* d_in, const int* in_sizes, int n_in,
                              void* d_out, int out_size, void* d_ws, size_t ws_size,
                              hipStream_t stream) {
    // d_in[0] = inputs (S x C) -- unused by the math (shape only), never read.
    const float* comp    = (const float*)d_in[1];  // K x C
    const float* contrib = (const float*)d_in[2];  // S x K
    const float* shift   = (const float*)d_in[3];  // S x K
    float* out = (float*)d_out;                    // S x C

    smf_kernel<<<S, BLOCK, 0, stream>>>(comp, contrib, shift, out);
}

// Round 5
// 95.519 us; speedup vs baseline: 1.1166x; 1.1139x over previous
//
#include <hip/hip_runtime.h>

// Problem constants (match reference setup_inputs()).
constexpr int S = 2048;   // N_SAMPLES
constexpr int C = 4096;   // N_CHANNELS
constexpr int K = 4;      // N_COMPONENTS

constexpr int BLOCK = 256;
constexpr int NQ = 4;                  // coalesced 4-channel chunks per thread
constexpr int QSTRIDE = BLOCK * 4;     // 1024 channels between a thread's chunks

// 4-byte-aligned float4: legal wide load for the gathered (dword-aligned but
// not 16B-aligned) component window.
typedef float f4u __attribute__((ext_vector_type(4), aligned(4)));
// Native 16B-aligned float vector for the coalesced stores.
typedef float f4n __attribute__((ext_vector_type(4)));

__global__ __launch_bounds__(BLOCK) void smf_kernel(
    const float* __restrict__ comp,      // K x C
    const float* __restrict__ contrib,   // S x K
    const float* __restrict__ shift,     // S x K
    float* __restrict__ out)             // S x C
{
    const int s = blockIdx.x;                  // one sample per block
    const int cbase = (int)threadIdx.x * 4;    // lane-contiguous 16B units

    // Per-sample params: blockIdx-uniform addresses -> scalar-load friendly.
    float w0[K], w1[K];
    int   m[K];
    int mmin = 1 << 30, mmax = -(1 << 30);
#pragma unroll
    for (int k = 0; k < K; ++k) {
        const float sh = shift[s * K + k];
        const float ct = contrib[s * K + k];
        const float mf = floorf(sh);
        const float f  = sh - mf;
        m[k]  = (int)mf;
        w0[k] = ct * (1.0f - f);
        w1[k] = ct * f;
        mmin = min(mmin, m[k]);
        mmax = max(mmax, m[k]);
    }

    // Each thread: NQ chunks of 4 channels, chunks 1024 channels apart.
    // Within a chunk every wave access is lane-contiguous (16B/lane) ->
    // fully coalesced loads AND stores (R2..R4's consecutive-16 layout made
    // every memory instruction touch 64 cache lines: +10us).
#pragma unroll
    for (int q = 0; q < NQ; ++q) {
        const int c = q * QSTRIDE + cbase;     // this chunk's first channel
        float4 acc = make_float4(0.f, 0.f, 0.f, 0.f);

        // Fast path: all tap indices for channels [c, c+3] in [0, C).
        const bool fast = (c + mmin >= 0) && (c + 4 + mmax < C);
        if (fast) {
#pragma unroll
            for (int k = 0; k < K; ++k) {
                const float* p = comp + k * C + c + m[k];
                const f4u  v = *(const f4u*)p;    // taps m for the 4 channels
                const float e = p[4];             // tap m+1 of channel c+3
                acc.x += w0[k] * v.x + w1[k] * v.y;
                acc.y += w0[k] * v.y + w1[k] * v.z;
                acc.z += w0[k] * v.z + w1[k] * v.w;
                acc.w += w0[k] * v.w + w1[k] * e;
            }
        } else {
            // Edge path (threads near channel 0 / C only): masked scalar
            // taps, exactly the reference semantics.
            float a[4] = {0.f, 0.f, 0.f, 0.f};
#pragma unroll
            for (int j = 0; j < 4; ++j) {
                const int cc = c + j;
#pragma unroll
                for (int k = 0; k < K; ++k) {
                    const int i0 = cc + m[k];
                    const int i1 = i0 + 1;
                    const float g0 = (i0 >= 0 && i0 < C) ? comp[k * C + i0] : 0.f;
                    const float g1 = (i1 >= 0 && i1 < C) ? comp[k * C + i1] : 0.f;
                    a[j] += w0[k] * g0 + w1[k] * g1;
                }
            }
            acc = make_float4(a[0], a[1], a[2], a[3]);
        }

        // Plain (cached) store: the 32 MB write-once output is absorbed by
        // L2/L3 at cache BW; nt-stores forced HBM inside the kernel (R3).
        f4n st = { acc.x, acc.y, acc.z, acc.w };
        *(f4n*)(out + s * C + c) = st;
    }
}

extern "C" void kernel_launch(void* const* d_in, const int* in_sizes, int n_in,
                              void* d_out, int out_size, void* d_ws, size_t ws_size,
                              hipStream_t stream) {
    // d_in[0] = inputs (S x C) -- unused by the math (shape only), never read.
    const float* comp    = (const float*)d_in[1];  // K x C
    const float* contrib = (const float*)d_in[2];  // S x K
    const float* shift   = (const float*)d_in[3];  // S x K
    float* out = (float*)d_out;                    // S x C

    smf_kernel<<<S, BLOCK, 0, stream>>>(comp, contrib, shift, out);
}